// Round 1
// baseline (1519.275 us; speedup 1.0000x reference)
//
#include <hip/hip_runtime.h>
#include <hip/hip_bf16.h>
#include <stdint.h>

#define T_TOK 8192
#define DIM   1024
#define FDIM  4096
#define NEXP  8
#define TKROWS (T_TOK * 2)   // total routed rows (top-2)

typedef float f32x4 __attribute__((ext_vector_type(4)));
typedef short s16x8 __attribute__((ext_vector_type(8)));

static __device__ __forceinline__ unsigned short f2bf(float f) {
    unsigned int u = __float_as_uint(f);
    unsigned int r = u + 0x7FFFu + ((u >> 16) & 1u);
    return (unsigned short)(r >> 16);
}

// ---- x f32 -> bf16 ----------------------------------------------------------
__global__ __launch_bounds__(256) void k_convert_x(const float4* __restrict__ x,
                                                   uint4* __restrict__ xb) {
    int i = blockIdx.x * 256 + threadIdx.x;      // each thread: 8 floats
    float4 a = x[2 * i], b = x[2 * i + 1];
    uint4 o;
    o.x = f2bf(a.x) | ((unsigned)f2bf(a.y) << 16);
    o.y = f2bf(a.z) | ((unsigned)f2bf(a.w) << 16);
    o.z = f2bf(b.x) | ((unsigned)f2bf(b.y) << 16);
    o.w = f2bf(b.z) | ((unsigned)f2bf(b.w) << 16);
    xb[i] = o;
}

// ---- router: softmax(x @ gate_w + gate_b), top-2 ----------------------------
__global__ __launch_bounds__(256) void k_router(const float* __restrict__ x,
                                                const float* __restrict__ gw,
                                                const float* __restrict__ gb,
                                                int* __restrict__ idx_arr,
                                                float* __restrict__ w_arr,
                                                int* __restrict__ cnt) {
    int lane = threadIdx.x & 63, w = threadIdx.x >> 6;
    int tok = blockIdx.x * 4 + w;
    const float* xr = x + (size_t)tok * DIM;
    float acc[8];
#pragma unroll
    for (int e = 0; e < 8; ++e) acc[e] = 0.f;
    for (int it = 0; it < DIM / 64; ++it) {
        int d = it * 64 + lane;
        float xv = xr[d];
        const float4* g = (const float4*)(gw + (size_t)d * 8);
        float4 g0 = g[0], g1 = g[1];
        acc[0] += xv * g0.x; acc[1] += xv * g0.y;
        acc[2] += xv * g0.z; acc[3] += xv * g0.w;
        acc[4] += xv * g1.x; acc[5] += xv * g1.y;
        acc[6] += xv * g1.z; acc[7] += xv * g1.w;
    }
#pragma unroll
    for (int off = 32; off; off >>= 1)
#pragma unroll
        for (int e = 0; e < 8; ++e) acc[e] += __shfl_xor(acc[e], off);
    if (lane == 0) {
        float l[8], m = -1e30f;
#pragma unroll
        for (int e = 0; e < 8; ++e) { l[e] = acc[e] + gb[e]; m = fmaxf(m, l[e]); }
        float s = 0.f, p[8];
#pragma unroll
        for (int e = 0; e < 8; ++e) { p[e] = expf(l[e] - m); s += p[e]; }
        float inv = 1.f / s;
#pragma unroll
        for (int e = 0; e < 8; ++e) p[e] *= inv;
        int i0 = 0;
#pragma unroll
        for (int e = 1; e < 8; ++e) if (p[e] > p[i0]) i0 = e;
        int i1 = (i0 == 0) ? 1 : 0;
#pragma unroll
        for (int e = 0; e < 8; ++e) if (e != i0 && p[e] > p[i1]) i1 = e;
        idx_arr[tok * 2 + 0] = i0;  w_arr[tok * 2 + 0] = p[i0];
        idx_arr[tok * 2 + 1] = i1;  w_arr[tok * 2 + 1] = p[i1];
        atomicAdd(&cnt[i0], 1);
        atomicAdd(&cnt[i1], 1);
    }
}

__global__ void k_scan(const int* __restrict__ cnt, int* __restrict__ offs) {
    if (threadIdx.x == 0) {
        int s = 0;
        for (int e = 0; e < NEXP; ++e) { offs[e] = s; s += cnt[e]; }
        offs[NEXP] = s;
    }
}

__global__ __launch_bounds__(256) void k_fill(const int* __restrict__ idx_arr,
                                              const float* __restrict__ w_arr,
                                              const int* __restrict__ offs,
                                              int* __restrict__ fill,
                                              int* __restrict__ row_token,
                                              float* __restrict__ row_w) {
    int t = blockIdx.x * 256 + threadIdx.x;
    if (t >= T_TOK) return;
#pragma unroll
    for (int k = 0; k < 2; ++k) {
        int e = idx_arr[t * 2 + k];
        int slot = atomicAdd(&fill[e], 1);
        int r = offs[e] + slot;
        row_token[r] = t;
        row_w[r] = w_arr[t * 2 + k];
    }
}

// ---- GEMM1: h = silu(x_gathered @ w1[e] + b1[e])  [M=ne, N=4096, K=1024] ----
__global__ __launch_bounds__(256) void k_gemm1(const ushort* __restrict__ xb,
                                               const float* __restrict__ w1,
                                               const float* __restrict__ b1,
                                               const int* __restrict__ cnt,
                                               const int* __restrict__ offs,
                                               const int* __restrict__ row_token,
                                               ushort* __restrict__ h) {
    int bid = blockIdx.x;
    int e  = bid >> 11;
    int ct = (bid >> 6) & 31;
    int rt = bid & 63;
    int ne = cnt[e];
    if (rt * 128 >= ne) return;
    int base = offs[e];

    __shared__ __align__(16) ushort As[128 * 72];
    __shared__ __align__(16) ushort Bs[128 * 72];

    int tid = threadIdx.x, lane = tid & 63, wid = tid >> 6;
    int wm = wid >> 1, wn = wid & 1;

    f32x4 acc[4][4];
    f32x4 z = {0.f, 0.f, 0.f, 0.f};
#pragma unroll
    for (int m = 0; m < 4; ++m)
#pragma unroll
        for (int n = 0; n < 4; ++n) acc[m][n] = z;

    // per-thread A staging rows + gathered tokens (constant over K loop)
    size_t abase[4];
    int akg[4];
#pragma unroll
    for (int g = 0; g < 4; ++g) {
        int u = tid + 256 * g;
        int row = u >> 3; akg[g] = u & 7;
        int grow = base + rt * 128 + row;
        grow = grow < TKROWS ? grow : TKROWS - 1;
        abase[g] = (size_t)row_token[grow] * DIM;
    }
    int arow_lds[4];
#pragma unroll
    for (int g = 0; g < 4; ++g) arow_lds[g] = ((tid + 256 * g) >> 3) * 72 + akg[g] * 8;

    const float* w1e = w1 + (size_t)e * DIM * FDIM + (size_t)ct * 128;
    int bn = tid & 127, kgb = tid >> 7;

    for (int kt = 0; kt < DIM / 64; ++kt) {
        // stage A (bf16, gathered rows)
#pragma unroll
        for (int g = 0; g < 4; ++g) {
            const uint4* src = (const uint4*)(xb + abase[g] + kt * 64 + akg[g] * 8);
            *(uint4*)&As[arow_lds[g]] = *src;
        }
        // stage B transposed, f32 -> bf16  (Bs[col][k])
#pragma unroll
        for (int g = 0; g < 8; ++g) {
            int k0 = (kgb + 2 * g) * 4;
            size_t rbase = (size_t)(kt * 64 + k0) * FDIM + bn;
            float v0 = w1e[rbase];
            float v1 = w1e[rbase + FDIM];
            float v2 = w1e[rbase + 2 * FDIM];
            float v3 = w1e[rbase + 3 * FDIM];
            uint2 pk;
            pk.x = f2bf(v0) | ((unsigned)f2bf(v1) << 16);
            pk.y = f2bf(v2) | ((unsigned)f2bf(v3) << 16);
            *(uint2*)&Bs[bn * 72 + k0] = pk;
        }
        __syncthreads();
#pragma unroll
        for (int ks = 0; ks < 2; ++ks) {
            s16x8 a[4], b[4];
#pragma unroll
            for (int m = 0; m < 4; ++m)
                a[m] = *(const s16x8*)&As[(wm * 64 + m * 16 + (lane & 15)) * 72 + ks * 32 + (lane >> 4) * 8];
#pragma unroll
            for (int n = 0; n < 4; ++n)
                b[n] = *(const s16x8*)&Bs[(wn * 64 + n * 16 + (lane & 15)) * 72 + ks * 32 + (lane >> 4) * 8];
#pragma unroll
            for (int m = 0; m < 4; ++m)
#pragma unroll
                for (int n = 0; n < 4; ++n)
                    acc[m][n] = __builtin_amdgcn_mfma_f32_16x16x32_bf16(a[m], b[n], acc[m][n], 0, 0, 0);
        }
        __syncthreads();
    }
    // epilogue: silu, store h (bf16)
#pragma unroll
    for (int m = 0; m < 4; ++m)
#pragma unroll
        for (int r = 0; r < 4; ++r) {
            int rloc = wm * 64 + m * 16 + ((lane >> 4) << 2) + r;
            int rexp = rt * 128 + rloc;
            if (rexp >= ne) continue;
            size_t hrow = (size_t)(base + rexp) * FDIM;
#pragma unroll
            for (int n = 0; n < 4; ++n) {
                int col = ct * 128 + wn * 64 + n * 16 + (lane & 15);
                float v = acc[m][n][r] + b1[e * FDIM + col];
                float si = v / (1.f + __expf(-v));
                h[hrow + col] = f2bf(si);
            }
        }
}

// ---- GEMM2: out[token] += w * (h @ w2[e] + b2[e])  [M=ne, N=1024, K=4096] ---
__global__ __launch_bounds__(256) void k_gemm2(const ushort* __restrict__ h,
                                               const float* __restrict__ w2,
                                               const float* __restrict__ b2,
                                               const int* __restrict__ cnt,
                                               const int* __restrict__ offs,
                                               const int* __restrict__ row_token,
                                               const float* __restrict__ row_w,
                                               float* __restrict__ out) {
    int bid = blockIdx.x;
    int e  = bid >> 9;
    int ct = (bid >> 6) & 7;
    int rt = bid & 63;
    int ne = cnt[e];
    if (rt * 128 >= ne) return;
    int base = offs[e];

    __shared__ __align__(16) ushort As[128 * 72];
    __shared__ __align__(16) ushort Bs[128 * 72];

    int tid = threadIdx.x, lane = tid & 63, wid = tid >> 6;
    int wm = wid >> 1, wn = wid & 1;

    f32x4 acc[4][4];
    f32x4 z = {0.f, 0.f, 0.f, 0.f};
#pragma unroll
    for (int m = 0; m < 4; ++m)
#pragma unroll
        for (int n = 0; n < 4; ++n) acc[m][n] = z;

    size_t abase[4];
    int akg[4], arow_lds[4];
#pragma unroll
    for (int g = 0; g < 4; ++g) {
        int u = tid + 256 * g;
        int row = u >> 3; akg[g] = u & 7;
        int grow = base + rt * 128 + row;
        grow = grow < TKROWS ? grow : TKROWS - 1;
        abase[g] = (size_t)grow * FDIM;
        arow_lds[g] = row * 72 + akg[g] * 8;
    }

    const float* w2e = w2 + (size_t)e * FDIM * DIM + (size_t)ct * 128;
    int bn = tid & 127, kgb = tid >> 7;

    for (int kt = 0; kt < FDIM / 64; ++kt) {
#pragma unroll
        for (int g = 0; g < 4; ++g) {
            const uint4* src = (const uint4*)(h + abase[g] + kt * 64 + akg[g] * 8);
            *(uint4*)&As[arow_lds[g]] = *src;
        }
#pragma unroll
        for (int g = 0; g < 8; ++g) {
            int k0 = (kgb + 2 * g) * 4;
            size_t rbase = (size_t)(kt * 64 + k0) * DIM + bn;
            float v0 = w2e[rbase];
            float v1 = w2e[rbase + DIM];
            float v2 = w2e[rbase + 2 * DIM];
            float v3 = w2e[rbase + 3 * DIM];
            uint2 pk;
            pk.x = f2bf(v0) | ((unsigned)f2bf(v1) << 16);
            pk.y = f2bf(v2) | ((unsigned)f2bf(v3) << 16);
            *(uint2*)&Bs[bn * 72 + k0] = pk;
        }
        __syncthreads();
#pragma unroll
        for (int ks = 0; ks < 2; ++ks) {
            s16x8 a[4], b[4];
#pragma unroll
            for (int m = 0; m < 4; ++m)
                a[m] = *(const s16x8*)&As[(wm * 64 + m * 16 + (lane & 15)) * 72 + ks * 32 + (lane >> 4) * 8];
#pragma unroll
            for (int n = 0; n < 4; ++n)
                b[n] = *(const s16x8*)&Bs[(wn * 64 + n * 16 + (lane & 15)) * 72 + ks * 32 + (lane >> 4) * 8];
#pragma unroll
            for (int m = 0; m < 4; ++m)
#pragma unroll
                for (int n = 0; n < 4; ++n)
                    acc[m][n] = __builtin_amdgcn_mfma_f32_16x16x32_bf16(a[m], b[n], acc[m][n], 0, 0, 0);
        }
        __syncthreads();
    }
#pragma unroll
    for (int m = 0; m < 4; ++m)
#pragma unroll
        for (int r = 0; r < 4; ++r) {
            int rloc = wm * 64 + m * 16 + ((lane >> 4) << 2) + r;
            int rexp = rt * 128 + rloc;
            if (rexp >= ne) continue;
            int rg = base + rexp;
            int tok = row_token[rg];
            float wgt = row_w[rg];
            float* orow = out + (size_t)tok * DIM;
#pragma unroll
            for (int n = 0; n < 4; ++n) {
                int col = ct * 128 + wn * 64 + n * 16 + (lane & 15);
                float v = acc[m][n][r] + b2[e * DIM + col];
                atomicAdd(&orow[col], wgt * v);
            }
        }
}

extern "C" void kernel_launch(void* const* d_in, const int* in_sizes, int n_in,
                              void* d_out, int out_size, void* d_ws, size_t ws_size,
                              hipStream_t stream) {
    const float* x      = (const float*)d_in[0];
    const float* gate_w = (const float*)d_in[1];
    const float* gate_b = (const float*)d_in[2];
    const float* w1     = (const float*)d_in[3];
    const float* b1     = (const float*)d_in[4];
    const float* w2     = (const float*)d_in[5];
    const float* b2     = (const float*)d_in[6];
    float* out = (float*)d_out;

    char* ws = (char*)d_ws;
    ushort* xb = (ushort*)ws;                               // 16 MiB
    size_t o = (size_t)T_TOK * DIM * 2;
    ushort* h = (ushort*)(ws + o);                          // 128 MiB
    o += (size_t)TKROWS * FDIM * 2;
    int*   idx_arr   = (int*)(ws + o);   o += TKROWS * 4;
    float* w_arr     = (float*)(ws + o); o += TKROWS * 4;
    int*   row_token = (int*)(ws + o);   o += TKROWS * 4;
    float* row_w     = (float*)(ws + o); o += TKROWS * 4;
    int*   cnt  = (int*)(ws + o);       // 8 ints
    int*   offs = cnt + 8;              // 9 ints
    int*   fill = cnt + 24;             // 8 ints

    hipMemsetAsync(out, 0, (size_t)T_TOK * DIM * 4, stream);
    hipMemsetAsync(cnt, 0, 256, stream);

    k_convert_x<<<4096, 256, 0, stream>>>((const float4*)x, (uint4*)xb);
    k_router<<<T_TOK / 4, 256, 0, stream>>>(x, gate_w, gate_b, idx_arr, w_arr, cnt);
    k_scan<<<1, 64, 0, stream>>>(cnt, offs);
    k_fill<<<T_TOK / 256, 256, 0, stream>>>(idx_arr, w_arr, offs, fill, row_token, row_w);
    k_gemm1<<<NEXP * 64 * 32, 256, 0, stream>>>(xb, w1, b1, cnt, offs, row_token, h);
    k_gemm2<<<NEXP * 64 * 8, 256, 0, stream>>>(h, w2, b2, cnt, offs, row_token, row_w, out);
}

// Round 2
// 1411.772 us; speedup vs baseline: 1.0761x; 1.0761x over previous
//
#include <hip/hip_runtime.h>
#include <hip/hip_bf16.h>
#include <stdint.h>

#define T_TOK 8192
#define DIM   1024
#define FDIM  4096
#define NEXP  8
#define TKROWS (T_TOK * 2)   // total routed rows (top-2)

typedef float f32x4 __attribute__((ext_vector_type(4)));
typedef short s16x8 __attribute__((ext_vector_type(8)));

#define GLDS16(g, l) __builtin_amdgcn_global_load_lds(                         \
    (const __attribute__((address_space(1))) void*)(g),                        \
    (__attribute__((address_space(3))) void*)(l), 16, 0, 0)

static __device__ __forceinline__ unsigned short f2bf(float f) {
    unsigned int u = __float_as_uint(f);
    unsigned int r = u + 0x7FFFu + ((u >> 16) & 1u);
    return (unsigned short)(r >> 16);
}

// ---- x f32 -> bf16 ----------------------------------------------------------
__global__ __launch_bounds__(256) void k_convert_x(const float4* __restrict__ x,
                                                   uint4* __restrict__ xb) {
    int i = blockIdx.x * 256 + threadIdx.x;      // each thread: 8 floats
    float4 a = x[2 * i], b = x[2 * i + 1];
    uint4 o;
    o.x = f2bf(a.x) | ((unsigned)f2bf(a.y) << 16);
    o.y = f2bf(a.z) | ((unsigned)f2bf(a.w) << 16);
    o.z = f2bf(b.x) | ((unsigned)f2bf(b.y) << 16);
    o.w = f2bf(b.z) | ((unsigned)f2bf(b.w) << 16);
    xb[i] = o;
}

// ---- weight transpose+convert: w [E][K][N] f32 -> wt [E][N][K] bf16 ---------
__global__ __launch_bounds__(256) void k_transpose(const float* __restrict__ w,
                                                   ushort* __restrict__ wt,
                                                   int K, int N) {
    int nt = N >> 6, ktl = K >> 6;
    int bid = blockIdx.x;
    int e = bid / (ktl * nt);
    int r = bid % (ktl * nt);
    int kb = r / nt, nb = r % nt;
    __shared__ ushort tile[64][65];
    const float* we = w + (size_t)e * K * N + (size_t)(kb * 64) * N + nb * 64;
    int t = threadIdx.x;
#pragma unroll
    for (int g = 0; g < 4; ++g) {
        int idx = t + g * 256;
        int row = idx >> 4, c4 = idx & 15;
        float4 v = *(const float4*)(we + (size_t)row * N + c4 * 4);
        tile[row][c4 * 4 + 0] = f2bf(v.x);
        tile[row][c4 * 4 + 1] = f2bf(v.y);
        tile[row][c4 * 4 + 2] = f2bf(v.z);
        tile[row][c4 * 4 + 3] = f2bf(v.w);
    }
    __syncthreads();
    ushort* wte = wt + (size_t)e * K * N + (size_t)(nb * 64) * K + kb * 64;
#pragma unroll
    for (int g = 0; g < 4; ++g) {
        int idx = t + g * 256;
        int n = idx >> 4, k4 = idx & 15;
        ushort4 o4;
        o4.x = tile[k4 * 4 + 0][n];
        o4.y = tile[k4 * 4 + 1][n];
        o4.z = tile[k4 * 4 + 2][n];
        o4.w = tile[k4 * 4 + 3][n];
        *(ushort4*)(wte + (size_t)n * K + k4 * 4) = o4;
    }
}

// ---- router: softmax(x @ gate_w + gate_b), top-2 ----------------------------
__global__ __launch_bounds__(256) void k_router(const float* __restrict__ x,
                                                const float* __restrict__ gw,
                                                const float* __restrict__ gb,
                                                int* __restrict__ idx_arr,
                                                float* __restrict__ w_arr,
                                                int* __restrict__ cnt) {
    int lane = threadIdx.x & 63, w = threadIdx.x >> 6;
    int tok = blockIdx.x * 4 + w;
    const float* xr = x + (size_t)tok * DIM;
    float acc[8];
#pragma unroll
    for (int e = 0; e < 8; ++e) acc[e] = 0.f;
    for (int it = 0; it < DIM / 64; ++it) {
        int d = it * 64 + lane;
        float xv = xr[d];
        const float4* g = (const float4*)(gw + (size_t)d * 8);
        float4 g0 = g[0], g1 = g[1];
        acc[0] += xv * g0.x; acc[1] += xv * g0.y;
        acc[2] += xv * g0.z; acc[3] += xv * g0.w;
        acc[4] += xv * g1.x; acc[5] += xv * g1.y;
        acc[6] += xv * g1.z; acc[7] += xv * g1.w;
    }
#pragma unroll
    for (int off = 32; off; off >>= 1)
#pragma unroll
        for (int e = 0; e < 8; ++e) acc[e] += __shfl_xor(acc[e], off);
    if (lane == 0) {
        float l[8], m = -1e30f;
#pragma unroll
        for (int e = 0; e < 8; ++e) { l[e] = acc[e] + gb[e]; m = fmaxf(m, l[e]); }
        float s = 0.f, p[8];
#pragma unroll
        for (int e = 0; e < 8; ++e) { p[e] = expf(l[e] - m); s += p[e]; }
        float inv = 1.f / s;
#pragma unroll
        for (int e = 0; e < 8; ++e) p[e] *= inv;
        int i0 = 0;
#pragma unroll
        for (int e = 1; e < 8; ++e) if (p[e] > p[i0]) i0 = e;
        int i1 = (i0 == 0) ? 1 : 0;
#pragma unroll
        for (int e = 0; e < 8; ++e) if (e != i0 && p[e] > p[i1]) i1 = e;
        idx_arr[tok * 2 + 0] = i0;  w_arr[tok * 2 + 0] = p[i0];
        idx_arr[tok * 2 + 1] = i1;  w_arr[tok * 2 + 1] = p[i1];
        atomicAdd(&cnt[i0], 1);
        atomicAdd(&cnt[i1], 1);
    }
}

__global__ void k_scan(const int* __restrict__ cnt, int* __restrict__ offs) {
    if (threadIdx.x == 0) {
        int s = 0;
        for (int e = 0; e < NEXP; ++e) { offs[e] = s; s += cnt[e]; }
        offs[NEXP] = s;
    }
}

__global__ __launch_bounds__(256) void k_fill(const int* __restrict__ idx_arr,
                                              const float* __restrict__ w_arr,
                                              const int* __restrict__ offs,
                                              int* __restrict__ fill,
                                              int* __restrict__ row_token,
                                              float* __restrict__ row_w) {
    int t = blockIdx.x * 256 + threadIdx.x;
    if (t >= T_TOK) return;
#pragma unroll
    for (int k = 0; k < 2; ++k) {
        int e = idx_arr[t * 2 + k];
        int slot = atomicAdd(&fill[e], 1);
        int r = offs[e] + slot;
        row_token[r] = t;
        row_w[r] = w_arr[t * 2 + k];
    }
}

// ---- GEMM1: h = silu(x_gathered @ w1t[e]^T + b1[e])  [M=ne, N=4096, K=1024] -
// m97 structure: 128x128 tile, BK=64, global_load_lds 16B, linear LDS.
__global__ __launch_bounds__(256) void k_gemm1(const ushort* __restrict__ xb,
                                               const ushort* __restrict__ w1t,
                                               const float* __restrict__ b1,
                                               const int* __restrict__ cnt,
                                               const int* __restrict__ offs,
                                               const int* __restrict__ row_token,
                                               ushort* __restrict__ h) {
    int bid = blockIdx.x;
    int e  = bid >> 11;          // 32 ct * 64 rt per expert
    int ct = (bid >> 6) & 31;
    int rt = bid & 63;
    int ne = cnt[e];
    if (rt * 128 >= ne) return;
    int base = offs[e];

    __shared__ __align__(16) ushort As[128 * 64];
    __shared__ __align__(16) ushort Bs[128 * 64];

    int tid = threadIdx.x, lane = tid & 63, wid = tid >> 6;
    int wm = wid >> 1, wn = wid & 1;

    // per-lane global sources; LDS dest is wave-uniform chunk base (+lane*16 by HW)
    const ushort* asrc[4];
    const ushort* bsrc[4];
    ushort* alds[4];
    ushort* blds[4];
    const ushort* w1e = w1t + (size_t)e * FDIM * DIM;
#pragma unroll
    for (int g = 0; g < 4; ++g) {
        int c = wid * 4 + g;               // chunk 0..15 (1024 B each)
        int o = c * 1024 + lane * 16;      // byte offset in 16 KB tile
        int row = o >> 7;                  // 128 B per row (64 bf16)
        int ko  = (o & 127) >> 1;
        int grow = base + rt * 128 + row;
        grow = grow < TKROWS ? grow : TKROWS - 1;
        asrc[g] = xb + (size_t)row_token[grow] * DIM + ko;
        bsrc[g] = w1e + (size_t)(ct * 128 + row) * DIM + ko;
        alds[g] = As + c * 512;
        blds[g] = Bs + c * 512;
    }

    f32x4 acc[4][4] = {};
    for (int kt = 0; kt < DIM / 64; ++kt) {
#pragma unroll
        for (int g = 0; g < 4; ++g) GLDS16(asrc[g] + kt * 64, alds[g]);
#pragma unroll
        for (int g = 0; g < 4; ++g) GLDS16(bsrc[g] + kt * 64, blds[g]);
        __syncthreads();
#pragma unroll
        for (int ks = 0; ks < 2; ++ks) {
            s16x8 a[4], b[4];
#pragma unroll
            for (int m = 0; m < 4; ++m)
                a[m] = *(const s16x8*)&As[(wm * 64 + m * 16 + (lane & 15)) * 64 + ks * 32 + (lane >> 4) * 8];
#pragma unroll
            for (int n = 0; n < 4; ++n)
                b[n] = *(const s16x8*)&Bs[(wn * 64 + n * 16 + (lane & 15)) * 64 + ks * 32 + (lane >> 4) * 8];
#pragma unroll
            for (int m = 0; m < 4; ++m)
#pragma unroll
                for (int n = 0; n < 4; ++n)
                    acc[m][n] = __builtin_amdgcn_mfma_f32_16x16x32_bf16(a[m], b[n], acc[m][n], 0, 0, 0);
        }
        __syncthreads();
    }

    const float* b1e = b1 + e * FDIM + ct * 128;
#pragma unroll
    for (int m = 0; m < 4; ++m) {
#pragma unroll
        for (int r = 0; r < 4; ++r) {
            int rloc = wm * 64 + m * 16 + ((lane >> 4) << 2) + r;
            int rexp = rt * 128 + rloc;
            if (rexp >= ne) continue;
            ushort* hrow = h + (size_t)(base + rexp) * FDIM + ct * 128;
#pragma unroll
            for (int n = 0; n < 4; ++n) {
                int col = wn * 64 + n * 16 + (lane & 15);
                float v = acc[m][n][r] + b1e[col];
                float si = v / (1.f + __expf(-v));
                hrow[col] = f2bf(si);
            }
        }
    }
}

// ---- GEMM2: out[token] += w * (h @ w2t[e]^T + b2[e])  [M=ne, N=1024, K=4096]
__global__ __launch_bounds__(256) void k_gemm2(const ushort* __restrict__ h,
                                               const ushort* __restrict__ w2t,
                                               const float* __restrict__ b2,
                                               const int* __restrict__ cnt,
                                               const int* __restrict__ offs,
                                               const int* __restrict__ row_token,
                                               const float* __restrict__ row_w,
                                               float* __restrict__ out) {
    int bid = blockIdx.x;
    int e  = bid >> 9;           // 8 ct * 64 rt per expert
    int ct = (bid >> 6) & 7;
    int rt = bid & 63;
    int ne = cnt[e];
    if (rt * 128 >= ne) return;
    int base = offs[e];

    __shared__ __align__(16) ushort As[128 * 64];
    __shared__ __align__(16) ushort Bs[128 * 64];

    int tid = threadIdx.x, lane = tid & 63, wid = tid >> 6;
    int wm = wid >> 1, wn = wid & 1;

    const ushort* asrc[4];
    const ushort* bsrc[4];
    ushort* alds[4];
    ushort* blds[4];
    const ushort* w2e = w2t + (size_t)e * DIM * FDIM;
#pragma unroll
    for (int g = 0; g < 4; ++g) {
        int c = wid * 4 + g;
        int o = c * 1024 + lane * 16;
        int row = o >> 7;
        int ko  = (o & 127) >> 1;
        int grow = base + rt * 128 + row;
        grow = grow < TKROWS ? grow : TKROWS - 1;
        asrc[g] = h + (size_t)grow * FDIM + ko;
        bsrc[g] = w2e + (size_t)(ct * 128 + row) * FDIM + ko;
        alds[g] = As + c * 512;
        blds[g] = Bs + c * 512;
    }

    f32x4 acc[4][4] = {};
    for (int kt = 0; kt < FDIM / 64; ++kt) {
#pragma unroll
        for (int g = 0; g < 4; ++g) GLDS16(asrc[g] + kt * 64, alds[g]);
#pragma unroll
        for (int g = 0; g < 4; ++g) GLDS16(bsrc[g] + kt * 64, blds[g]);
        __syncthreads();
#pragma unroll
        for (int ks = 0; ks < 2; ++ks) {
            s16x8 a[4], b[4];
#pragma unroll
            for (int m = 0; m < 4; ++m)
                a[m] = *(const s16x8*)&As[(wm * 64 + m * 16 + (lane & 15)) * 64 + ks * 32 + (lane >> 4) * 8];
#pragma unroll
            for (int n = 0; n < 4; ++n)
                b[n] = *(const s16x8*)&Bs[(wn * 64 + n * 16 + (lane & 15)) * 64 + ks * 32 + (lane >> 4) * 8];
#pragma unroll
            for (int m = 0; m < 4; ++m)
#pragma unroll
                for (int n = 0; n < 4; ++n)
                    acc[m][n] = __builtin_amdgcn_mfma_f32_16x16x32_bf16(a[m], b[n], acc[m][n], 0, 0, 0);
        }
        __syncthreads();
    }

    const float* b2e = b2 + e * DIM + ct * 128;
#pragma unroll
    for (int m = 0; m < 4; ++m) {
#pragma unroll
        for (int r = 0; r < 4; ++r) {
            int rloc = wm * 64 + m * 16 + ((lane >> 4) << 2) + r;
            int rexp = rt * 128 + rloc;
            if (rexp >= ne) continue;
            int rg = base + rexp;
            int tok = row_token[rg];
            float wgt = row_w[rg];
            float* orow = out + (size_t)tok * DIM + ct * 128;
#pragma unroll
            for (int n = 0; n < 4; ++n) {
                int col = wn * 64 + n * 16 + (lane & 15);
                atomicAdd(&orow[col], wgt * (acc[m][n][r] + b2e[col]));
            }
        }
    }
}

extern "C" void kernel_launch(void* const* d_in, const int* in_sizes, int n_in,
                              void* d_out, int out_size, void* d_ws, size_t ws_size,
                              hipStream_t stream) {
    const float* x      = (const float*)d_in[0];
    const float* gate_w = (const float*)d_in[1];
    const float* gate_b = (const float*)d_in[2];
    const float* w1     = (const float*)d_in[3];
    const float* b1     = (const float*)d_in[4];
    const float* w2     = (const float*)d_in[5];
    const float* b2     = (const float*)d_in[6];
    float* out = (float*)d_out;

    char* ws = (char*)d_ws;
    size_t o = 0;
    ushort* wt = (ushort*)(ws + o); o += (size_t)NEXP * DIM * FDIM * 2;  // 67 MB, shared w1t then w2t
    ushort* xb = (ushort*)(ws + o); o += (size_t)T_TOK * DIM * 2;        // 16.8 MB
    ushort* h  = (ushort*)(ws + o); o += (size_t)TKROWS * FDIM * 2;      // 134 MB
    int*   idx_arr   = (int*)(ws + o);   o += TKROWS * 4;
    float* w_arr     = (float*)(ws + o); o += TKROWS * 4;
    int*   row_token = (int*)(ws + o);   o += TKROWS * 4;
    float* row_w     = (float*)(ws + o); o += TKROWS * 4;
    int*   cnt  = (int*)(ws + o);       // 8 ints
    int*   offs = cnt + 8;              // 9 ints
    int*   fill = cnt + 24;             // 8 ints

    hipMemsetAsync(out, 0, (size_t)T_TOK * DIM * 4, stream);
    hipMemsetAsync(cnt, 0, 256, stream);

    k_convert_x<<<4096, 256, 0, stream>>>((const float4*)x, (uint4*)xb);
    k_router<<<T_TOK / 4, 256, 0, stream>>>(x, gate_w, gate_b, idx_arr, w_arr, cnt);
    k_scan<<<1, 64, 0, stream>>>(cnt, offs);
    k_fill<<<T_TOK / 256, 256, 0, stream>>>(idx_arr, w_arr, offs, fill, row_token, row_w);

    k_transpose<<<NEXP * (DIM / 64) * (FDIM / 64), 256, 0, stream>>>(w1, wt, DIM, FDIM);
    k_gemm1<<<NEXP * 64 * 32, 256, 0, stream>>>(xb, wt, b1, cnt, offs, row_token, h);
    k_transpose<<<NEXP * (FDIM / 64) * (DIM / 64), 256, 0, stream>>>(w2, wt, FDIM, DIM);
    k_gemm2<<<NEXP * 64 * 8, 256, 0, stream>>>(h, wt, b2, cnt, offs, row_token, row_w, out);
}